// Round 8
// baseline (236.425 us; speedup 1.0000x reference)
//
#include <hip/hip_runtime.h>
#include <math.h>

// Problem constants (fixed by reference setup_inputs)
#define L0   4448   // flux length
#define L1P  278    // after conv1(stride4,pad7)->1112 then maxpool4
#define L2   139    // after conv2(stride2,pad3) on 278
#define NQ   8
#define NL   3
#define SD   256

// R17: two samples/block (iA=2b, iB=2b+1) with SHARED flux buffer and
// ALL WEIGHTS IN REGISTERS (consumption-layout global loads) -> LDS 33.9 KB,
// 4 blocks/CU. Stage 1 runs twice (A from LDS while B parked in regs; B's
// packed bf16 ds_written into fxb after pass A). Stages 2/proj/tail keep the
// R16 A/B per-thread interleave (ILP x2).
//
// LDS word map (float S[8480] = 33920 B):
//  fxb   bf16[4496]  el 0..4495   (w0..2247)  flux at el x+8; els 0..7 & 4456..4495 zero
//  h1T_A bf16[286][20] el 4496..10215 (w2248..5107)  rows 0..3 & 282..285 zero
//  h1T_B bf16[286][20] el 10216..15935 (w5108..7967) rows 0..3 & 282..285 zero
//  featU_A f32[256]  w7968..8223  (s_U alias after proj1 — R4 invariant)
//  featU_B f32[256]  w8224..8479
// Stage-2 overreads (masked by j>138): h1T_A rows 286..294 -> h1T_B rows 0..8;
// h1T_B rows 286..294 -> featU_A words (garbage bf16, value-masked, in-bounds).
// Stage-1 fxb overread (el<=4507) -> h1T_A rows 0..3 (zero).
// Post-stage-2 aliases in dead fxb: s_hiddenA w0..63, s_hiddenB w64..127,
// s_redA w128..131, s_redB w132..135, wpA w136..163, wpB w164..191,
// s_qA w192..199, s_qB w200..207, ampcA (float2[256]) w256..767,
// ampcB w768..1279.
#define H1TA_EL 4496
#define H1TB_EL 10216
#define FTWA    7968
#define FTWB    8224

typedef __attribute__((ext_vector_type(4))) short short4v;
typedef __attribute__((ext_vector_type(8))) short short8;
typedef __attribute__((ext_vector_type(4))) float f32x4;
union FragU { short8 v; short4v h[2]; };

__device__ __forceinline__ short f2bf(float x) {   // fp32 -> bf16 (RNE)
    unsigned u = __float_as_uint(x);
    u += 0x7FFFu + ((u >> 16) & 1u);
    return (short)(u >> 16);
}

__device__ __forceinline__ short8 pack8(float4 a, float4 b) {
    short8 v;
    v[0] = f2bf(a.x); v[1] = f2bf(a.y); v[2] = f2bf(a.z); v[3] = f2bf(a.w);
    v[4] = f2bf(b.x); v[5] = f2bf(b.y); v[6] = f2bf(b.z); v[7] = f2bf(b.w);
    return v;
}

// CNOT-ring permutation (one layer of 8 CNOTs composed). Linear over GF(2).
constexpr int permsrc_c(int x) {
    for (int q = 7; q >= 0; --q) {
        int cb = 7 - q, tb = 7 - ((q + 1) & 7);
        x ^= ((x >> cb) & 1) << tb;
    }
    return x;
}
constexpr int P40 = permsrc_c(0x40);
constexpr int P80 = permsrc_c(0x80);
constexpr int PC0 = permsrc_c(0xC0);   // == P40 ^ P80 (GF(2)-linear)

__device__ __forceinline__ int permsrc(int x) {
    #pragma unroll
    for (int q = 7; q >= 0; --q) {
        int cb = 7 - q, tb = 7 - ((q + 1) & 7);
        x ^= ((x >> cb) & 1) << tb;
    }
    return x;
}

__global__ __launch_bounds__(256, 4)
void aec_fused_kernel(const float* __restrict__ flux,
                      const float* __restrict__ scalars,
                      const float* __restrict__ conv1_w,
                      const float* __restrict__ bn1_g, const float* __restrict__ bn1_b,
                      const float* __restrict__ conv2_w,
                      const float* __restrict__ bn2_g, const float* __restrict__ bn2_b,
                      const float* __restrict__ proj_w1, const float* __restrict__ proj_b1,
                      const float* __restrict__ proj_w2, const float* __restrict__ proj_b2,
                      const float* __restrict__ qw,
                      const float* __restrict__ head_w1, const float* __restrict__ head_b1,
                      const float* __restrict__ head_bn_g, const float* __restrict__ head_bn_b,
                      const float* __restrict__ head_w2, const float* __restrict__ head_b2,
                      float* __restrict__ out)
{
    const int iA  = 2 * blockIdx.x;
    const int iB  = iA + 1;
    const int tid = threadIdx.x;

    __shared__ __align__(16) float S[8480];

    float* s_hiddenA = S;            // w0..63
    float* s_hiddenB = S + 64;       // w64..127
    float* s_redA    = S + 128;      // w128..131
    float* s_redB    = S + 132;      // w132..135
    float* wpA       = S + 136;      // w136..163 (Walsh parts [4][7])
    float* wpB       = S + 164;      // w164..191
    float* s_qA      = S + 192;      // w192..199
    float* s_qB      = S + 200;      // w200..207
    float* featUA    = S + FTWA;
    float* featUB    = S + FTWB;
    float* s_U       = S + FTWA;     // gates overwrite featU_A AFTER proj1 (R4 inv.)

    const float BN_RSQ = 0.9999950000374997f;     // 1/sqrt(1+1e-5)

    const int lane = tid & 63;
    const int wid  = tid >> 6;
    const int col  = lane & 15;
    const int quad = lane >> 4;

    // ---------------- stage 0: zeros + reg weights + flux staging -------------
    featUA[tid] = 0.0f;
    featUB[tid] = 0.0f;
    if (tid < 4)        S[tid] = 0.0f;          // fxb els 0..7
    else if (tid < 64)  S[2224 + tid] = 0.0f;   // fxb tail + h1T_A rows 0..3
    else if (tid < 144) S[5004 + tid] = 0.0f;   // h1T_A rows 282..285 + h1T_B rows 0..3
    else if (tid < 184) S[7784 + tid] = 0.0f;   // h1T_B rows 282..285

    // conv1 fragment (consumption layout; sign-flipped so bn1 scale >= 0 and
    // maxpool commutes with the affine — exact, R14-verified).
    const float gsc = fabsf(bn1_g[col]) * BN_RSQ;
    const float gbt = bn1_b[col];
    short8 wfrag;
    {
        const float sgn = (bn1_g[col] >= 0.0f) ? 1.0f : -1.0f;
        #pragma unroll
        for (int e = 0; e < 8; ++e) {
            const int kp = quad * 8 + e;          // k' taps 1..15 valid
            wfrag[e] = (kp >= 1 && kp <= 15)
                       ? f2bf(sgn * conv1_w[col * 15 + kp - 1]) : (short)0;
        }
    }
    // conv2 fragments (consumption layout, R12 mapping: K'=kb*32+quad*8+e ->
    // k=2kb+(quad>>1), ic=(quad&1)*8+e; k==7 zero pad).
    short8 wa0[4], wa1[4];
    {
        #pragma unroll
        for (int kb = 0; kb < 4; ++kb) {
            const int k   = 2 * kb + (quad >> 1);
            const int ic0 = (quad & 1) * 8;
            #pragma unroll
            for (int e = 0; e < 8; ++e) {
                wa0[kb][e] = (k < 7) ? f2bf(conv2_w[col * 112 + (ic0 + e) * 7 + k]) : (short)0;
                wa1[kb][e] = (k < 7) ? f2bf(conv2_w[(col + 16) * 112 + (ic0 + e) * 7 + k]) : (short)0;
            }
        }
    }
    // flux B -> packed bf16 REGISTERS (fxb still holds A until pass A done)
    short8 fb0, fb1, fb2 = {0,0,0,0,0,0,0,0};
    {
        const float4* fgB = (const float4*)(flux + (size_t)iB * L0);
        fb0 = pack8(fgB[2 * tid],         fgB[2 * tid + 1]);
        fb1 = pack8(fgB[2 * (tid + 256)], fgB[2 * (tid + 256) + 1]);
        if (tid < 44)
            fb2 = pack8(fgB[2 * (tid + 512)], fgB[2 * (tid + 512) + 1]);
    }
    // flux A -> bf16 LDS (el x+8)
    {
        const float4* fgA = (const float4*)(flux + (size_t)iA * L0);
        short* fx = (short*)S;
        *(short8*)(fx + 8 + 8 * tid) =
            pack8(fgA[2 * tid], fgA[2 * tid + 1]);
        *(short8*)(fx + 8 + 8 * (tid + 256)) =
            pack8(fgA[2 * (tid + 256)], fgA[2 * (tid + 256) + 1]);
        if (tid < 44)
            *(short8*)(fx + 8 + 8 * (tid + 512)) =
                pack8(fgA[2 * (tid + 512)], fgA[2 * (tid + 512) + 1]);
    }
    __syncthreads();

    // ---------------- stage 1 pass A: conv1(A) + pool + bn (R9-verified) ------
    {
        const short* fx = (const short*)S;
        for (int nt = wid; nt < 70; nt += 4) {
            const int jl = nt * 16 + col;
            FragU xu;
            xu.h[0] = *(const short4v*)(fx + 4 * jl + quad * 8);
            xu.h[1] = *(const short4v*)(fx + 4 * jl + quad * 8 + 4);
            f32x4 acc = {0.f, 0.f, 0.f, 0.f};
            acc = __builtin_amdgcn_mfma_f32_16x16x32_bf16(xu.v, wfrag, acc, 0, 0, 0);
            const float m = fmaxf(fmaxf(acc[0], acc[1]), fmaxf(acc[2], acc[3]));
            const int p = nt * 4 + quad;
            if (p < L1P)
                *((short*)S + H1TA_EL + (4 + p) * 20 + col) =
                    f2bf(fmaxf(m * gsc + gbt, 0.0f));
        }
    }
    __syncthreads();   // all fxb(A) reads done

    // flux B regs -> fxb (overwrite dead A flux)
    {
        short* fx = (short*)S;
        *(short8*)(fx + 8 + 8 * tid)         = fb0;
        *(short8*)(fx + 8 + 8 * (tid + 256)) = fb1;
        if (tid < 44) *(short8*)(fx + 8 + 8 * (tid + 512)) = fb2;
    }
    __syncthreads();   // fxb = flux B

    // ---------------- stage 1 pass B ------------------------------------------
    {
        const short* fx = (const short*)S;
        for (int nt = wid; nt < 70; nt += 4) {
            const int jl = nt * 16 + col;
            FragU xu;
            xu.h[0] = *(const short4v*)(fx + 4 * jl + quad * 8);
            xu.h[1] = *(const short4v*)(fx + 4 * jl + quad * 8 + 4);
            f32x4 acc = {0.f, 0.f, 0.f, 0.f};
            acc = __builtin_amdgcn_mfma_f32_16x16x32_bf16(xu.v, wfrag, acc, 0, 0, 0);
            const float m = fmaxf(fmaxf(acc[0], acc[1]), fmaxf(acc[2], acc[3]));
            const int p = nt * 4 + quad;
            if (p < L1P)
                *((short*)S + H1TB_EL + (4 + p) * 20 + col) =
                    f2bf(fmaxf(m * gsc + gbt, 0.0f));
        }
    }
    __syncthreads();   // h1T_A/B complete; fxb now dead

    // ---------------- stage 2: conv2 MFMA + bn/relu + pool (A/B interleaved) ---
    // (R9/R12-verified) weights already in regs (wa0/wa1).
    {
        const short* h1sA = (const short*)S + H1TA_EL;
        const short* h1sB = (const short*)S + H1TB_EL;
        const float sc0 = bn2_g[col] * BN_RSQ,      bt0 = bn2_b[col];
        const float sc1 = bn2_g[col + 16] * BN_RSQ, bt1 = bn2_b[col + 16];

        for (int nt = wid; nt < 9; nt += 4) {
            const int n0 = nt * 16;
            f32x4 accA0 = {0.f,0.f,0.f,0.f}, accA1 = {0.f,0.f,0.f,0.f};
            f32x4 accB0 = {0.f,0.f,0.f,0.f}, accB1 = {0.f,0.f,0.f,0.f};
            #pragma unroll
            for (int kb = 0; kb < 4; ++kb) {
                const int k   = 2 * kb + (quad >> 1);
                const int ic0 = (quad & 1) * 8;
                const int row = 2 * (n0 + col) + 1 + k;
                FragU buA, buB;
                buA.h[0] = *(const short4v*)(h1sA + row * 20 + ic0);
                buA.h[1] = *(const short4v*)(h1sA + row * 20 + ic0 + 4);
                buB.h[0] = *(const short4v*)(h1sB + row * 20 + ic0);
                buB.h[1] = *(const short4v*)(h1sB + row * 20 + ic0 + 4);
                accA0 = __builtin_amdgcn_mfma_f32_16x16x32_bf16(buA.v, wa0[kb], accA0, 0, 0, 0);
                accA1 = __builtin_amdgcn_mfma_f32_16x16x32_bf16(buA.v, wa1[kb], accA1, 0, 0, 0);
                accB0 = __builtin_amdgcn_mfma_f32_16x16x32_bf16(buB.v, wa0[kb], accB0, 0, 0, 0);
                accB1 = __builtin_amdgcn_mfma_f32_16x16x32_bf16(buB.v, wa1[kb], accB1, 0, 0, 0);
            }
            const int   bk  = (8 * n0) / 139;
            const int   sBd = (139 * (bk + 1)) >> 3;      // j<=sBd -> bk; j>=sBd -> bk+1
            const float rc0 = (bk == 2 || bk == 5) ? (1.0f/19.0f) : (1.0f/18.0f);
            const float rc1 = (bk == 1 || bk == 4) ? (1.0f/19.0f) : (1.0f/18.0f);
            float vaA0 = 0.f, vbA0 = 0.f, vaA1 = 0.f, vbA1 = 0.f;
            float vaB0 = 0.f, vbB0 = 0.f, vaB1 = 0.f, vbB1 = 0.f;
            #pragma unroll
            for (int r = 0; r < 4; ++r) {
                const int j = n0 + quad * 4 + r;
                float vA0 = fmaxf(accA0[r] * sc0 + bt0, 0.0f);
                float vA1 = fmaxf(accA1[r] * sc1 + bt1, 0.0f);
                float vB0 = fmaxf(accB0[r] * sc0 + bt0, 0.0f);
                float vB1 = fmaxf(accB1[r] * sc1 + bt1, 0.0f);
                if (j > 138) { vA0 = 0.0f; vA1 = 0.0f; vB0 = 0.0f; vB1 = 0.0f; }
                if (j <= sBd) { vaA0 += vA0; vaA1 += vA1; vaB0 += vB0; vaB1 += vB1; }
                if (j >= sBd) { vbA0 += vA0; vbA1 += vA1; vbB0 += vB0; vbB1 += vB1; }
            }
            vaA0 += __shfl_xor(vaA0, 16, 64); vaA0 += __shfl_xor(vaA0, 32, 64);
            vaA1 += __shfl_xor(vaA1, 16, 64); vaA1 += __shfl_xor(vaA1, 32, 64);
            vbA0 += __shfl_xor(vbA0, 16, 64); vbA0 += __shfl_xor(vbA0, 32, 64);
            vbA1 += __shfl_xor(vbA1, 16, 64); vbA1 += __shfl_xor(vbA1, 32, 64);
            vaB0 += __shfl_xor(vaB0, 16, 64); vaB0 += __shfl_xor(vaB0, 32, 64);
            vaB1 += __shfl_xor(vaB1, 16, 64); vaB1 += __shfl_xor(vaB1, 32, 64);
            vbB0 += __shfl_xor(vbB0, 16, 64); vbB0 += __shfl_xor(vbB0, 32, 64);
            vbB1 += __shfl_xor(vbB1, 16, 64); vbB1 += __shfl_xor(vbB1, 32, 64);
            if (quad == 0) {
                atomicAdd(&featUA[col * 8 + bk],        vaA0 * rc0);
                atomicAdd(&featUA[(col + 16) * 8 + bk], vaA1 * rc0);
                atomicAdd(&featUB[col * 8 + bk],        vaB0 * rc0);
                atomicAdd(&featUB[(col + 16) * 8 + bk], vaB1 * rc0);
                if (bk < 7) {
                    atomicAdd(&featUA[col * 8 + bk + 1],        vbA0 * rc1);
                    atomicAdd(&featUA[(col + 16) * 8 + bk + 1], vbA1 * rc1);
                    atomicAdd(&featUB[col * 8 + bk + 1],        vbB0 * rc1);
                    atomicAdd(&featUB[(col + 16) * 8 + bk + 1], vbB1 * rc1);
                }
            }
        }
    }
    __syncthreads();

    // ---------------- proj1 (256 -> 64), relu — shared weights, 2 dots --------
    {
        const int o = tid >> 2, s = tid & 3;
        const float4* wg  = (const float4*)(proj_w1 + 64 * tid);   // == o*256 + s*64
        const float4* xfA = (const float4*)(featUA + 64 * s);
        const float4* xfB = (const float4*)(featUB + 64 * s);
        float accA = 0.0f, accB = 0.0f;
        #pragma unroll
        for (int t = 0; t < 16; ++t) {
            float4 w4 = wg[t], a4 = xfA[t], b4 = xfB[t];
            accA += w4.x * a4.x + w4.y * a4.y + w4.z * a4.z + w4.w * a4.w;
            accB += w4.x * b4.x + w4.y * b4.y + w4.z * b4.z + w4.w * b4.w;
        }
        accA += __shfl_down(accA, 2, 64); accB += __shfl_down(accB, 2, 64);
        accA += __shfl_down(accA, 1, 64); accB += __shfl_down(accB, 1, 64);
        if (s == 0) {
            s_hiddenA[o] = fmaxf(accA + proj_b1[o], 0.0f);
            s_hiddenB[o] = fmaxf(accB + proj_b1[o], 0.0f);
        }
    }
    __syncthreads();

    // gate matrices into featU_A alias (published by the norm barrier below)
    if (tid < NL * NQ) {
        float phi = qw[tid * 3 + 0], th = qw[tid * 3 + 1], om = qw[tid * 3 + 2];
        float ch = cosf(0.5f * th), sh = sinf(0.5f * th);
        float a  = 0.5f * (phi + om), bb = 0.5f * (phi - om);
        float ca = cosf(a), sa = sinf(a), cb = cosf(bb), sb = sinf(bb);
        float* U = &s_U[tid * 8];
        U[0] =  ca * ch; U[1] = -sa * ch;   // U00
        U[2] = -cb * sh; U[3] = -sb * sh;   // U01
        U[4] =  cb * sh; U[5] = -sb * sh;   // U10
        U[6] =  ca * ch; U[7] =  sa * ch;   // U11
    }

    // ---------------- proj2 (64 -> 256) + L2 normalize (A/B interleaved) ------
    float reA, reB;
    {
        const float4* wg  = (const float4*)(proj_w2 + 64 * tid);
        const float4* hfA = (const float4*)s_hiddenA;
        const float4* hfB = (const float4*)s_hiddenB;
        float accA = proj_b2[tid], accB = accA;
        #pragma unroll
        for (int t = 0; t < 16; ++t) {
            float4 w4 = wg[t], a4 = hfA[t], b4 = hfB[t];
            accA += w4.x * a4.x + w4.y * a4.y + w4.z * a4.z + w4.w * a4.w;
            accB += w4.x * b4.x + w4.y * b4.y + w4.z * b4.z + w4.w * b4.w;
        }
        float ssA = accA * accA, ssB = accB * accB;
        #pragma unroll
        for (int off = 32; off >= 1; off >>= 1) {
            ssA += __shfl_xor(ssA, off, 64);
            ssB += __shfl_xor(ssB, off, 64);
        }
        if ((tid & 63) == 0) { s_redA[tid >> 6] = ssA; s_redB[tid >> 6] = ssB; }
        __syncthreads();                           // also publishes s_U
        float sstA = s_redA[0] + s_redA[1] + s_redA[2] + s_redA[3];
        float sstB = s_redB[0] + s_redB[1] + s_redB[2] + s_redB[3];
        float nA = sqrtf(sstA), nB = sqrtf(sstB);
        float invA = 1.0f / fmaxf(nA, 1e-12f);
        float invB = 1.0f / fmaxf(nB, 1e-12f);
        float xiA = accA * invA, xiB = accB * invB;
        if (nA * invA < 1e-8f) xiA = 0.0625f;      // uniform 1/sqrt(256)
        if (nB * invB < 1e-8f) xiB = 0.0625f;
        reA = xiA; reB = xiB;                      // initial state real (im = 0)
    }

    // ---------------- tail: 4-wave circuit, A/B interleaved (R15/R16) ---------
    float2* ampcA = (float2*)(S + 256);   // w256..767
    float2* ampcB = (float2*)(S + 768);   // w768..1279

    const int w    = tid >> 6;
    const int b7   = w >> 1, b6 = w & 1;
    const int sl   = permsrc(lane);                      // may set bits 6,7
    const int pw   = (b6 ? P40 : 0) ^ (b7 ? P80 : 0);    // permsrc(w<<6)

    ampcA[tid] = make_float2(reA, 0.0f);
    ampcB[tid] = make_float2(reB, 0.0f);
    __syncthreads();           // amps + s_U visible to all waves

    float arA = 0.0f, aiA = 0.0f, arB = 0.0f, aiB = 0.0f;
    #pragma unroll
    for (int l = 0; l < NL; ++l) {
        // --- exchange + combined q=0 (bit7), q=1 (bit6) gates ---
        float oAr[4], oAi[4], oBr[4], oBi[4];
        #pragma unroll
        for (int j = 0; j < 4; ++j) {
            const int src = (l == 0) ? (lane + 64 * j)
                                     : (sl ^ ((j & 1 ? P40 : 0) ^ (j & 2 ? P80 : 0)));
            const float2 vA = ampcA[src];
            const float2 vB = ampcB[src];
            oAr[j] = vA.x; oAi[j] = (l == 0) ? 0.0f : vA.y;
            oBr[j] = vB.x; oBi[j] = (l == 0) ? 0.0f : vB.y;
        }
        {
            const float* U0 = &s_U[(l * NQ + 0) * 8];
            const float* U1 = &s_U[(l * NQ + 1) * 8];
            const float a0r = b7 ? U0[4] : U0[0], a0i = b7 ? U0[5] : U0[1];
            const float a1r = b7 ? U0[6] : U0[2], a1i = b7 ? U0[7] : U0[3];
            const float c0r = b6 ? U1[4] : U1[0], c0i = b6 ? U1[5] : U1[1];
            const float c1r = b6 ? U1[6] : U1[2], c1i = b6 ? U1[7] : U1[3];
            // A
            const float tA0r = a0r*oAr[0] - a0i*oAi[0] + a1r*oAr[2] - a1i*oAi[2];
            const float tA0i = a0r*oAi[0] + a0i*oAr[0] + a1r*oAi[2] + a1i*oAr[2];
            const float tA1r = a0r*oAr[1] - a0i*oAi[1] + a1r*oAr[3] - a1i*oAi[3];
            const float tA1i = a0r*oAi[1] + a0i*oAr[1] + a1r*oAi[3] + a1i*oAr[3];
            arA = c0r*tA0r - c0i*tA0i + c1r*tA1r - c1i*tA1i;
            aiA = c0r*tA0i + c0i*tA0r + c1r*tA1i + c1i*tA1r;
            // B
            const float tB0r = a0r*oBr[0] - a0i*oBi[0] + a1r*oBr[2] - a1i*oBi[2];
            const float tB0i = a0r*oBi[0] + a0i*oBr[0] + a1r*oBi[2] + a1i*oBr[2];
            const float tB1r = a0r*oBr[1] - a0i*oBi[1] + a1r*oBr[3] - a1i*oBi[3];
            const float tB1i = a0r*oBi[1] + a0i*oBr[1] + a1r*oBi[3] + a1i*oBr[3];
            arB = c0r*tB0r - c0i*tB0i + c1r*tB1r - c1i*tB1i;
            aiB = c0r*tB0i + c0i*tB0r + c1r*tB1i + c1i*tB1r;
        }
        // --- q=2..7: lane-bit gates via shuffles, A/B chains interleaved ---
        #pragma unroll
        for (int q = 2; q < NQ; ++q) {
            const float* U = &s_U[(l * NQ + q) * 8];
            const int bp  = 7 - q;
            const int bit = (lane >> bp) & 1;
            const float csr = bit ? U[6] : U[0];
            const float csi = bit ? U[7] : U[1];
            const float cpr = bit ? U[4] : U[2];
            const float cpi = bit ? U[5] : U[3];
            const float pAr = __shfl_xor(arA, 1 << bp, 64);
            const float pAi = __shfl_xor(aiA, 1 << bp, 64);
            const float pBr = __shfl_xor(arB, 1 << bp, 64);
            const float pBi = __shfl_xor(aiB, 1 << bp, 64);
            const float nAr = csr * arA - csi * aiA + cpr * pAr - cpi * pAi;
            const float nAi = csr * aiA + csi * arA + cpr * pAi + cpi * pAr;
            const float nBr = csr * arB - csi * aiB + cpr * pBr - cpi * pBi;
            const float nBi = csr * aiB + csi * arB + cpr * pBi + cpi * pBr;
            arA = nAr; aiA = nAi; arB = nBr; aiB = nBi;
        }
        __syncthreads();                 // all reads of ampc done before overwrite
        ampcA[tid] = make_float2(arA, aiA);
        ampcB[tid] = make_float2(arB, aiB);
        __syncthreads();                 // writes visible for next read
    }

    // final CNOT-ring of layer 3: read own permuted amp
    {
        const float2 vA = ampcA[sl ^ pw];
        const float2 vB = ampcB[sl ^ pw];
        arA = vA.x; aiA = vA.y; arB = vB.x; aiB = vB.y;
    }

    // Walsh-Hadamard: per-wave signed butterfly (R10-verified), A/B interleaved
    {
        const float pA = arA * arA + aiA * aiA;
        const float pB = arB * arB + aiB * aiB;
        float tA = pA, tB = pB;
        #pragma unroll
        for (int d = 0; d < 6; ++d) {
            const float sAs = __shfl_xor(tA, 1 << d, 64);
            const float sBs = __shfl_xor(tB, 1 << d, 64);
            tA = ((lane >> d) & 1) ? (sAs - tA) : (tA + sAs);
            tB = ((lane >> d) & 1) ? (sBs - tB) : (tB + sBs);
        }
        if (lane == 0) { wpA[w * 7] = tA; wpB[w * 7] = tB; }
        else if ((lane & (lane - 1)) == 0) {
            const int d = 31 - __clz(lane);                 // lane = 1<<d, d 0..5
            wpA[w * 7 + 1 + d] = tA;                        // qubit 7-d partial
            wpB[w * 7 + 1 + d] = tB;
        }
    }
    __syncthreads();           // wp visible; waves 2-3 exit after this

    // wave 0 -> sample A, wave 1 -> sample B (independent heads in parallel)
    if (tid < 128) {
        const int sm = tid >> 6;
        const float* wpp = sm ? wpB : wpA;
        float* sq        = sm ? s_qB : s_qA;
        const int bb     = sm ? iB : iA;
        // combine Walsh parts -> s_q (same-wave LDS, program-ordered)
        if (lane < 8) {
            float v;
            if (lane == 0)      v = wpp[0] + wpp[7] - wpp[14] - wpp[21];   // bit7
            else if (lane == 1) v = wpp[0] - wpp[7] + wpp[14] - wpp[21];   // bit6
            else {
                const int d = 7 - lane;                                     // q=2..7
                v = wpp[1 + d] + wpp[8 + d] + wpp[15 + d] + wpp[22 + d];
            }
            sq[lane] = v;
        }
        // head layer 1 (lanes 0..31; sq read-after-write, same wave)
        float h = 0.0f;
        if (lane < 32) {
            float acc = head_b1[lane];
            #pragma unroll
            for (int k = 0; k < 8; ++k) acc += head_w1[lane * 14 + k] * sq[k];
            #pragma unroll
            for (int k = 0; k < 6; ++k) acc += head_w1[lane * 14 + 8 + k] * scalars[bb * 6 + k];
            h = fmaxf(acc * (head_bn_g[lane] * BN_RSQ) + head_bn_b[lane], 0.0f);
        }
        // head layer 2: 3 dot-products over 32 h values via butterfly reduce
        float p0 = (lane < 32) ? h * head_w2[lane]      : 0.0f;
        float p1 = (lane < 32) ? h * head_w2[32 + lane] : 0.0f;
        float p2 = (lane < 32) ? h * head_w2[64 + lane] : 0.0f;
        #pragma unroll
        for (int d = 0; d < 6; ++d) {
            p0 += __shfl_xor(p0, 1 << d, 64);
            p1 += __shfl_xor(p1, 1 << d, 64);
            p2 += __shfl_xor(p2, 1 << d, 64);
        }
        if (lane < 3) {
            const float v = (lane == 0) ? p0 : ((lane == 1) ? p1 : p2);
            out[bb * 3 + lane] = v + head_b2[lane];
        }
    }
}

extern "C" void kernel_launch(void* const* d_in, const int* in_sizes, int n_in,
                              void* d_out, int out_size, void* d_ws, size_t ws_size,
                              hipStream_t stream) {
    const float* flux      = (const float*)d_in[0];
    const float* scalars   = (const float*)d_in[1];
    const float* conv1_w   = (const float*)d_in[2];
    const float* bn1_g     = (const float*)d_in[3];
    const float* bn1_b     = (const float*)d_in[4];
    const float* conv2_w   = (const float*)d_in[5];
    const float* bn2_g     = (const float*)d_in[6];
    const float* bn2_b     = (const float*)d_in[7];
    const float* proj_w1   = (const float*)d_in[8];
    const float* proj_b1   = (const float*)d_in[9];
    const float* proj_w2   = (const float*)d_in[10];
    const float* proj_b2   = (const float*)d_in[11];
    const float* q_weights = (const float*)d_in[12];
    const float* head_w1   = (const float*)d_in[13];
    const float* head_b1   = (const float*)d_in[14];
    const float* head_bn_g = (const float*)d_in[15];
    const float* head_bn_b = (const float*)d_in[16];
    const float* head_w2   = (const float*)d_in[17];
    const float* head_b2   = (const float*)d_in[18];

    const int B = in_sizes[0] / L0;   // 4096

    aec_fused_kernel<<<dim3(B / 2), dim3(256), 0, stream>>>(
        flux, scalars, conv1_w, bn1_g, bn1_b, conv2_w, bn2_g, bn2_b,
        proj_w1, proj_b1, proj_w2, proj_b2, q_weights,
        head_w1, head_b1, head_bn_g, head_bn_b, head_w2, head_b2,
        (float*)d_out);
}

// Round 9
// 210.752 us; speedup vs baseline: 1.1218x; 1.1218x over previous
//
#include <hip/hip_runtime.h>
#include <math.h>

// Problem constants (fixed by reference setup_inputs)
#define L0   4448   // flux length
#define L1P  278    // after conv1(stride4,pad7)->1112 then maxpool4
#define L2   139    // after conv2(stride2,pad3) on 278
#define NQ   8
#define NL   3
#define SD   256

// R18: THREE samples per block (i=3b..3b+2), mirrored LDS regions SA/SB/SC of
// RGN=5620 words (R16 internal map). Weights shared: Wc1+Wb in SA only, s_U in
// SA only, proj/head weights loaded once and dotted 3x (ILP x3).
// Dynamic LDS: 3*5620*4 = 67440 B -> 2 blocks/CU.
//
// Per-region map (words rel. region base):
//  fxb  bf16[4496] el 0..4495 (w0..2247); h1T bf16[286][20] el 4496..10215
//  (w2248..5107, rows 0..3 & 282..285 zero); WC1 slot el 10216..10727
//  (SA: conv1 weights; SB/SC: garbage, only hit by masked stage-2 overread);
//  featU f32[256] w5364..5619 (SA's aliases s_U after proj1 — R4 invariant).
//  Wb bf16[32][136] el 0..4351 in SA's dead fxb (written after stage 1).
// Post-stage-2 aliases in SA's dead fxb/Wb (w0..2247):
//  s_hiddenA w0..63, s_hiddenB w64..127, s_hiddenC w128..191,
//  s_redA w192..195, s_redB w196..199, s_redC w200..203,
//  wpA w204..231, wpB w232..259, wpC w260..287,
//  s_qA w288..295, s_qB w296..303, s_qC w304..311,
//  ampcA (float2[256]) w320..831, ampcB w832..1343, ampcC w1344..1855.
#define H1T_EL 4496
#define WB_EL  0
#define WC1_EL 10216
#define FTW    5364
#define RGN    5620
#define SHBYTES (3 * RGN * 4)

typedef __attribute__((ext_vector_type(4))) short short4v;
typedef __attribute__((ext_vector_type(8))) short short8;
typedef __attribute__((ext_vector_type(4))) float f32x4;
union FragU { short8 v; short4v h[2]; };

__device__ __forceinline__ short f2bf(float x) {   // fp32 -> bf16 (RNE)
    unsigned u = __float_as_uint(x);
    u += 0x7FFFu + ((u >> 16) & 1u);
    return (short)(u >> 16);
}

__device__ __forceinline__ short8 pack8(float4 a, float4 b) {
    short8 v;
    v[0] = f2bf(a.x); v[1] = f2bf(a.y); v[2] = f2bf(a.z); v[3] = f2bf(a.w);
    v[4] = f2bf(b.x); v[5] = f2bf(b.y); v[6] = f2bf(b.z); v[7] = f2bf(b.w);
    return v;
}

// CNOT-ring permutation (one layer of 8 CNOTs composed). Linear over GF(2).
constexpr int permsrc_c(int x) {
    for (int q = 7; q >= 0; --q) {
        int cb = 7 - q, tb = 7 - ((q + 1) & 7);
        x ^= ((x >> cb) & 1) << tb;
    }
    return x;
}
constexpr int P40 = permsrc_c(0x40);
constexpr int P80 = permsrc_c(0x80);
constexpr int PC0 = permsrc_c(0xC0);   // == P40 ^ P80 (GF(2)-linear)

__device__ __forceinline__ int permsrc(int x) {
    #pragma unroll
    for (int q = 7; q >= 0; --q) {
        int cb = 7 - q, tb = 7 - ((q + 1) & 7);
        x ^= ((x >> cb) & 1) << tb;
    }
    return x;
}

__global__ __launch_bounds__(256, 2)
void aec_fused_kernel(const float* __restrict__ flux,
                      const float* __restrict__ scalars,
                      const float* __restrict__ conv1_w,
                      const float* __restrict__ bn1_g, const float* __restrict__ bn1_b,
                      const float* __restrict__ conv2_w,
                      const float* __restrict__ bn2_g, const float* __restrict__ bn2_b,
                      const float* __restrict__ proj_w1, const float* __restrict__ proj_b1,
                      const float* __restrict__ proj_w2, const float* __restrict__ proj_b2,
                      const float* __restrict__ qw,
                      const float* __restrict__ head_w1, const float* __restrict__ head_b1,
                      const float* __restrict__ head_bn_g, const float* __restrict__ head_bn_b,
                      const float* __restrict__ head_w2, const float* __restrict__ head_b2,
                      float* __restrict__ out, int Btot)
{
    const int iA  = 3 * blockIdx.x;
    const int iB  = iA + 1;
    const int iC  = iA + 2;
    const int iBc = (iB < Btot) ? iB : (Btot - 1);   // clamped load indices
    const int iCc = (iC < Btot) ? iC : (Btot - 1);
    const int tid = threadIdx.x;

    extern __shared__ float S2[];
    float* SA = S2;
    float* SB = S2 + RGN;
    float* SC = S2 + 2 * RGN;

    float* s_hiddenA = SA;           float* s_hiddenB = SA + 64;   float* s_hiddenC = SA + 128;
    float* s_redA    = SA + 192;     float* s_redB    = SA + 196;  float* s_redC    = SA + 200;
    float* wpA       = SA + 204;     float* wpB       = SA + 232;  float* wpC       = SA + 260;
    float* s_qA      = SA + 288;     float* s_qB      = SA + 296;  float* s_qC      = SA + 304;
    float* featUA    = SA + FTW;     float* featUB    = SB + FTW;  float* featUC    = SC + FTW;
    float* s_U       = SA + FTW;     // gates overwrite featU_A AFTER proj1 (R4 inv.)

    const float BN_RSQ = 0.9999950000374997f;     // 1/sqrt(1+1e-5)

    // ---------------- stage 0: zeros + weight staging + flux staging ----------
    featUA[tid] = 0.0f; featUB[tid] = 0.0f; featUC[tid] = 0.0f;
    if (tid < 4) {
        SA[tid] = 0.0f; SB[tid] = 0.0f; SC[tid] = 0.0f;
    } else if (tid < 64) {
        SA[2224 + tid] = 0.0f; SB[2224 + tid] = 0.0f; SC[2224 + tid] = 0.0f;
    } else if (tid < 104) {
        SA[5004 + tid] = 0.0f; SB[5004 + tid] = 0.0f; SC[5004 + tid] = 0.0f;
    }
    {
        // Wc1 (SHARED, SA only): k'=0 zero, k'=1..15 = sgn*conv1_w, 16..31 zero.
        // Sign flip (exact) keeps every effective bn1 scale >= 0 so maxpool
        // commutes with the affine.
        const int oc = tid >> 4;
        const int q  = tid & 15;
        const float sgn = (bn1_g[oc] >= 0.0f) ? 1.0f : -1.0f;
        const int k0 = 2 * q, k1 = 2 * q + 1;
        const short e0 = (k0 >= 1 && k0 <= 15) ? f2bf(sgn * conv1_w[oc * 15 + k0 - 1]) : (short)0;
        const short e1 = (k1 <= 15)            ? f2bf(sgn * conv1_w[oc * 15 + k1 - 1]) : (short)0;
        const unsigned pk = (unsigned short)e0 | ((unsigned)(unsigned short)e1 << 16);
        *(unsigned*)((short*)SA + WC1_EL + oc * 32 + 2 * q) = pk;
    }
    // Wb prefetch to REGISTERS (SHARED; ds_write into dead fxb_A after stage 1).
    short8 wbp0, wbp1;
    {
        const int oc = tid >> 3;
        const int k  = tid & 7;
        #pragma unroll
        for (int e = 0; e < 8; ++e) {
            wbp0[e] = (k < 7) ? f2bf(conv2_w[oc * 112 + e * 7 + k])       : (short)0;
            wbp1[e] = (k < 7) ? f2bf(conv2_w[oc * 112 + (8 + e) * 7 + k]) : (short)0;
        }
    }
    {
        // flux -> bf16 LDS for all THREE samples (3x outstanding loads).
        const float4* fgA = (const float4*)(flux + (size_t)iA  * L0);
        const float4* fgB = (const float4*)(flux + (size_t)iBc * L0);
        const float4* fgC = (const float4*)(flux + (size_t)iCc * L0);
        short* fxA = (short*)SA;
        short* fxB = (short*)SB;
        short* fxC = (short*)SC;
        for (int t = tid; t < 556; t += 256) {
            float4 a0 = fgA[2 * t], a1 = fgA[2 * t + 1];
            float4 b0 = fgB[2 * t], b1 = fgB[2 * t + 1];
            float4 c0 = fgC[2 * t], c1 = fgC[2 * t + 1];
            *(short8*)(fxA + 8 + 8 * t) = pack8(a0, a1);
            *(short8*)(fxB + 8 + 8 * t) = pack8(b0, b1);
            *(short8*)(fxC + 8 + 8 * t) = pack8(c0, c1);
        }
    }
    __syncthreads();

    const int lane = tid & 63;
    const int wid  = tid >> 6;
    const int col  = lane & 15;
    const int quad = lane >> 4;

    // ---------------- stage 1: conv1 MFMA + pool + bn, A/B/C interleaved ------
    // (R9-verified) D[j][oc] = X^T[16 j][32 k'] x Wc1^T[32][16 oc].
    {
        const short* fxA = (const short*)SA;
        const short* fxB = (const short*)SB;
        const short* fxC = (const short*)SC;
        const short8 wfrag = *(const short8*)((const short*)SA + WC1_EL + col * 32 + quad * 8);
        const float gsc = fabsf(bn1_g[col]) * BN_RSQ;
        const float gbt = bn1_b[col];

        for (int nt = wid; nt < 70; nt += 4) {
            const int jl = nt * 16 + col;
            FragU xuA, xuB, xuC;
            xuA.h[0] = *(const short4v*)(fxA + 4 * jl + quad * 8);
            xuA.h[1] = *(const short4v*)(fxA + 4 * jl + quad * 8 + 4);
            xuB.h[0] = *(const short4v*)(fxB + 4 * jl + quad * 8);
            xuB.h[1] = *(const short4v*)(fxB + 4 * jl + quad * 8 + 4);
            xuC.h[0] = *(const short4v*)(fxC + 4 * jl + quad * 8);
            xuC.h[1] = *(const short4v*)(fxC + 4 * jl + quad * 8 + 4);
            f32x4 accA = {0.f,0.f,0.f,0.f}, accB = {0.f,0.f,0.f,0.f}, accC = {0.f,0.f,0.f,0.f};
            accA = __builtin_amdgcn_mfma_f32_16x16x32_bf16(xuA.v, wfrag, accA, 0, 0, 0);
            accB = __builtin_amdgcn_mfma_f32_16x16x32_bf16(xuB.v, wfrag, accB, 0, 0, 0);
            accC = __builtin_amdgcn_mfma_f32_16x16x32_bf16(xuC.v, wfrag, accC, 0, 0, 0);
            const float mA = fmaxf(fmaxf(accA[0], accA[1]), fmaxf(accA[2], accA[3]));
            const float mB = fmaxf(fmaxf(accB[0], accB[1]), fmaxf(accB[2], accB[3]));
            const float mC = fmaxf(fmaxf(accC[0], accC[1]), fmaxf(accC[2], accC[3]));
            const int p = nt * 4 + quad;
            if (p < L1P) {
                *((short*)SA + H1T_EL + (4 + p) * 20 + col) = f2bf(fmaxf(mA * gsc + gbt, 0.0f));
                *((short*)SB + H1T_EL + (4 + p) * 20 + col) = f2bf(fmaxf(mB * gsc + gbt, 0.0f));
                *((short*)SC + H1T_EL + (4 + p) * 20 + col) = f2bf(fmaxf(mC * gsc + gbt, 0.0f));
            }
        }
    }
    __syncthreads();   // h1T_A/B/C complete; fxb regions dead

    // Wb[oc][K'=k*16+ic] bf16, row stride 136 (k==7 row zero) -> dead fxb_A.
    {
        const int oc = tid >> 3;
        const int k  = tid & 7;
        short8* dst = (short8*)((char*)SA + (WB_EL + oc * 136 + k * 16) * 2);
        dst[0] = wbp0; dst[1] = wbp1;
    }
    __syncthreads();   // Wb ready; featU regions still pure pool sums

    // ---------------- stage 2: conv2 MFMA + bn/relu + pool, A/B/C interleaved --
    // (R9/R12-verified) D[j][oc] = X^T[144 j][128] x Wb^T[128][32 oc].
    {
        const short* h1sA = (const short*)SA + H1T_EL;
        const short* h1sB = (const short*)SB + H1T_EL;
        const short* h1sC = (const short*)SC + H1T_EL;
        const char*  wbc  = (const char*)((const short*)SA + WB_EL);
        const float sc0 = bn2_g[col] * BN_RSQ,      bt0 = bn2_b[col];
        const float sc1 = bn2_g[col + 16] * BN_RSQ, bt1 = bn2_b[col + 16];

        short8 wa0[4], wa1[4];
        #pragma unroll
        for (int kb = 0; kb < 4; ++kb) {
            wa0[kb] = *(const short8*)(wbc + (col * 136        + kb*32 + quad*8) * 2);
            wa1[kb] = *(const short8*)(wbc + ((16 + col) * 136 + kb*32 + quad*8) * 2);
        }

        for (int nt = wid; nt < 9; nt += 4) {
            const int n0 = nt * 16;
            f32x4 aA0 = {0.f,0.f,0.f,0.f}, aA1 = {0.f,0.f,0.f,0.f};
            f32x4 aB0 = {0.f,0.f,0.f,0.f}, aB1 = {0.f,0.f,0.f,0.f};
            f32x4 aC0 = {0.f,0.f,0.f,0.f}, aC1 = {0.f,0.f,0.f,0.f};
            #pragma unroll
            for (int kb = 0; kb < 4; ++kb) {
                const int k   = 2 * kb + (quad >> 1);
                const int ic0 = (quad & 1) * 8;
                const int row = 2 * (n0 + col) + 1 + k;
                FragU buA, buB, buC;
                buA.h[0] = *(const short4v*)(h1sA + row * 20 + ic0);
                buA.h[1] = *(const short4v*)(h1sA + row * 20 + ic0 + 4);
                buB.h[0] = *(const short4v*)(h1sB + row * 20 + ic0);
                buB.h[1] = *(const short4v*)(h1sB + row * 20 + ic0 + 4);
                buC.h[0] = *(const short4v*)(h1sC + row * 20 + ic0);
                buC.h[1] = *(const short4v*)(h1sC + row * 20 + ic0 + 4);
                aA0 = __builtin_amdgcn_mfma_f32_16x16x32_bf16(buA.v, wa0[kb], aA0, 0, 0, 0);
                aA1 = __builtin_amdgcn_mfma_f32_16x16x32_bf16(buA.v, wa1[kb], aA1, 0, 0, 0);
                aB0 = __builtin_amdgcn_mfma_f32_16x16x32_bf16(buB.v, wa0[kb], aB0, 0, 0, 0);
                aB1 = __builtin_amdgcn_mfma_f32_16x16x32_bf16(buB.v, wa1[kb], aB1, 0, 0, 0);
                aC0 = __builtin_amdgcn_mfma_f32_16x16x32_bf16(buC.v, wa0[kb], aC0, 0, 0, 0);
                aC1 = __builtin_amdgcn_mfma_f32_16x16x32_bf16(buC.v, wa1[kb], aC1, 0, 0, 0);
            }
            const int   bk  = (8 * n0) / 139;
            const int   sBd = (139 * (bk + 1)) >> 3;      // j<=sBd -> bk; j>=sBd -> bk+1
            const float rc0 = (bk == 2 || bk == 5) ? (1.0f/19.0f) : (1.0f/18.0f);
            const float rc1 = (bk == 1 || bk == 4) ? (1.0f/19.0f) : (1.0f/18.0f);
            float vaA0=0.f,vbA0=0.f,vaA1=0.f,vbA1=0.f;
            float vaB0=0.f,vbB0=0.f,vaB1=0.f,vbB1=0.f;
            float vaC0=0.f,vbC0=0.f,vaC1=0.f,vbC1=0.f;
            #pragma unroll
            for (int r = 0; r < 4; ++r) {
                const int j = n0 + quad * 4 + r;
                float vA0 = fmaxf(aA0[r] * sc0 + bt0, 0.0f);
                float vA1 = fmaxf(aA1[r] * sc1 + bt1, 0.0f);
                float vB0 = fmaxf(aB0[r] * sc0 + bt0, 0.0f);
                float vB1 = fmaxf(aB1[r] * sc1 + bt1, 0.0f);
                float vC0 = fmaxf(aC0[r] * sc0 + bt0, 0.0f);
                float vC1 = fmaxf(aC1[r] * sc1 + bt1, 0.0f);
                if (j > 138) { vA0=0.f; vA1=0.f; vB0=0.f; vB1=0.f; vC0=0.f; vC1=0.f; }
                if (j <= sBd) { vaA0+=vA0; vaA1+=vA1; vaB0+=vB0; vaB1+=vB1; vaC0+=vC0; vaC1+=vC1; }
                if (j >= sBd) { vbA0+=vA0; vbA1+=vA1; vbB0+=vB0; vbB1+=vB1; vbC0+=vC0; vbC1+=vC1; }
            }
            vaA0 += __shfl_xor(vaA0,16,64); vaA0 += __shfl_xor(vaA0,32,64);
            vaA1 += __shfl_xor(vaA1,16,64); vaA1 += __shfl_xor(vaA1,32,64);
            vbA0 += __shfl_xor(vbA0,16,64); vbA0 += __shfl_xor(vbA0,32,64);
            vbA1 += __shfl_xor(vbA1,16,64); vbA1 += __shfl_xor(vbA1,32,64);
            vaB0 += __shfl_xor(vaB0,16,64); vaB0 += __shfl_xor(vaB0,32,64);
            vaB1 += __shfl_xor(vaB1,16,64); vaB1 += __shfl_xor(vaB1,32,64);
            vbB0 += __shfl_xor(vbB0,16,64); vbB0 += __shfl_xor(vbB0,32,64);
            vbB1 += __shfl_xor(vbB1,16,64); vbB1 += __shfl_xor(vbB1,32,64);
            vaC0 += __shfl_xor(vaC0,16,64); vaC0 += __shfl_xor(vaC0,32,64);
            vaC1 += __shfl_xor(vaC1,16,64); vaC1 += __shfl_xor(vaC1,32,64);
            vbC0 += __shfl_xor(vbC0,16,64); vbC0 += __shfl_xor(vbC0,32,64);
            vbC1 += __shfl_xor(vbC1,16,64); vbC1 += __shfl_xor(vbC1,32,64);
            if (quad == 0) {
                atomicAdd(&featUA[col * 8 + bk],        vaA0 * rc0);
                atomicAdd(&featUA[(col + 16) * 8 + bk], vaA1 * rc0);
                atomicAdd(&featUB[col * 8 + bk],        vaB0 * rc0);
                atomicAdd(&featUB[(col + 16) * 8 + bk], vaB1 * rc0);
                atomicAdd(&featUC[col * 8 + bk],        vaC0 * rc0);
                atomicAdd(&featUC[(col + 16) * 8 + bk], vaC1 * rc0);
                if (bk < 7) {
                    atomicAdd(&featUA[col * 8 + bk + 1],        vbA0 * rc1);
                    atomicAdd(&featUA[(col + 16) * 8 + bk + 1], vbA1 * rc1);
                    atomicAdd(&featUB[col * 8 + bk + 1],        vbB0 * rc1);
                    atomicAdd(&featUB[(col + 16) * 8 + bk + 1], vbB1 * rc1);
                    atomicAdd(&featUC[col * 8 + bk + 1],        vbC0 * rc1);
                    atomicAdd(&featUC[(col + 16) * 8 + bk + 1], vbC1 * rc1);
                }
            }
        }
    }
    __syncthreads();

    // ---------------- proj1 (256 -> 64), relu — shared weights, 3 dots --------
    {
        const int o = tid >> 2, s = tid & 3;
        const float4* wg  = (const float4*)(proj_w1 + 64 * tid);   // == o*256 + s*64
        const float4* xfA = (const float4*)(featUA + 64 * s);
        const float4* xfB = (const float4*)(featUB + 64 * s);
        const float4* xfC = (const float4*)(featUC + 64 * s);
        float accA = 0.0f, accB = 0.0f, accC = 0.0f;
        #pragma unroll
        for (int t = 0; t < 16; ++t) {
            float4 w4 = wg[t], a4 = xfA[t], b4 = xfB[t], c4 = xfC[t];
            accA += w4.x * a4.x + w4.y * a4.y + w4.z * a4.z + w4.w * a4.w;
            accB += w4.x * b4.x + w4.y * b4.y + w4.z * b4.z + w4.w * b4.w;
            accC += w4.x * c4.x + w4.y * c4.y + w4.z * c4.z + w4.w * c4.w;
        }
        accA += __shfl_down(accA, 2, 64); accB += __shfl_down(accB, 2, 64); accC += __shfl_down(accC, 2, 64);
        accA += __shfl_down(accA, 1, 64); accB += __shfl_down(accB, 1, 64); accC += __shfl_down(accC, 1, 64);
        if (s == 0) {
            s_hiddenA[o] = fmaxf(accA + proj_b1[o], 0.0f);
            s_hiddenB[o] = fmaxf(accB + proj_b1[o], 0.0f);
            s_hiddenC[o] = fmaxf(accC + proj_b1[o], 0.0f);
        }
    }
    __syncthreads();

    // gate matrices into featU_A alias (SHARED; published by norm barrier below)
    if (tid < NL * NQ) {
        float phi = qw[tid * 3 + 0], th = qw[tid * 3 + 1], om = qw[tid * 3 + 2];
        float ch = cosf(0.5f * th), sh = sinf(0.5f * th);
        float a  = 0.5f * (phi + om), bb = 0.5f * (phi - om);
        float ca = cosf(a), sa = sinf(a), cb = cosf(bb), sb = sinf(bb);
        float* U = &s_U[tid * 8];
        U[0] =  ca * ch; U[1] = -sa * ch;   // U00
        U[2] = -cb * sh; U[3] = -sb * sh;   // U01
        U[4] =  cb * sh; U[5] = -sb * sh;   // U10
        U[6] =  ca * ch; U[7] =  sa * ch;   // U11
    }

    // ---------------- proj2 (64 -> 256) + L2 normalize (A/B/C interleaved) ----
    float reA, reB, reC;
    {
        const float4* wg  = (const float4*)(proj_w2 + 64 * tid);
        const float4* hfA = (const float4*)s_hiddenA;
        const float4* hfB = (const float4*)s_hiddenB;
        const float4* hfC = (const float4*)s_hiddenC;
        float accA = proj_b2[tid], accB = accA, accC = accA;
        #pragma unroll
        for (int t = 0; t < 16; ++t) {
            float4 w4 = wg[t], a4 = hfA[t], b4 = hfB[t], c4 = hfC[t];
            accA += w4.x * a4.x + w4.y * a4.y + w4.z * a4.z + w4.w * a4.w;
            accB += w4.x * b4.x + w4.y * b4.y + w4.z * b4.z + w4.w * b4.w;
            accC += w4.x * c4.x + w4.y * c4.y + w4.z * c4.z + w4.w * c4.w;
        }
        float ssA = accA * accA, ssB = accB * accB, ssC = accC * accC;
        #pragma unroll
        for (int off = 32; off >= 1; off >>= 1) {
            ssA += __shfl_xor(ssA, off, 64);
            ssB += __shfl_xor(ssB, off, 64);
            ssC += __shfl_xor(ssC, off, 64);
        }
        if ((tid & 63) == 0) {
            s_redA[tid >> 6] = ssA; s_redB[tid >> 6] = ssB; s_redC[tid >> 6] = ssC;
        }
        __syncthreads();                           // also publishes s_U
        float sstA = s_redA[0] + s_redA[1] + s_redA[2] + s_redA[3];
        float sstB = s_redB[0] + s_redB[1] + s_redB[2] + s_redB[3];
        float sstC = s_redC[0] + s_redC[1] + s_redC[2] + s_redC[3];
        float nA = sqrtf(sstA), nB = sqrtf(sstB), nC = sqrtf(sstC);
        float invA = 1.0f / fmaxf(nA, 1e-12f);
        float invB = 1.0f / fmaxf(nB, 1e-12f);
        float invC = 1.0f / fmaxf(nC, 1e-12f);
        float xiA = accA * invA, xiB = accB * invB, xiC = accC * invC;
        if (nA * invA < 1e-8f) xiA = 0.0625f;      // uniform 1/sqrt(256)
        if (nB * invB < 1e-8f) xiB = 0.0625f;
        if (nC * invC < 1e-8f) xiC = 0.0625f;
        reA = xiA; reB = xiB; reC = xiC;           // initial state real (im = 0)
    }

    // ---------------- tail: 4-wave circuit, A/B/C interleaved (R15/R16) -------
    float2* ampcA = (float2*)(SA + 320);    // w320..831
    float2* ampcB = (float2*)(SA + 832);    // w832..1343
    float2* ampcC = (float2*)(SA + 1344);   // w1344..1855

    const int w    = tid >> 6;
    const int b7   = w >> 1, b6 = w & 1;
    const int sl   = permsrc(lane);                      // may set bits 6,7
    const int pw   = (b6 ? P40 : 0) ^ (b7 ? P80 : 0);    // permsrc(w<<6)

    ampcA[tid] = make_float2(reA, 0.0f);
    ampcB[tid] = make_float2(reB, 0.0f);
    ampcC[tid] = make_float2(reC, 0.0f);
    __syncthreads();           // amps + s_U visible to all waves

    float arA = 0.f, aiA = 0.f, arB = 0.f, aiB = 0.f, arC = 0.f, aiC = 0.f;
    #pragma unroll
    for (int l = 0; l < NL; ++l) {
        // --- exchange + combined q=0 (bit7), q=1 (bit6) gates ---
        float oAr[4], oAi[4], oBr[4], oBi[4], oCr[4], oCi[4];
        #pragma unroll
        for (int j = 0; j < 4; ++j) {
            const int src = (l == 0) ? (lane + 64 * j)
                                     : (sl ^ ((j & 1 ? P40 : 0) ^ (j & 2 ? P80 : 0)));
            const float2 vA = ampcA[src];
            const float2 vB = ampcB[src];
            const float2 vC = ampcC[src];
            oAr[j] = vA.x; oAi[j] = (l == 0) ? 0.0f : vA.y;
            oBr[j] = vB.x; oBi[j] = (l == 0) ? 0.0f : vB.y;
            oCr[j] = vC.x; oCi[j] = (l == 0) ? 0.0f : vC.y;
        }
        {
            const float* U0 = &s_U[(l * NQ + 0) * 8];
            const float* U1 = &s_U[(l * NQ + 1) * 8];
            const float a0r = b7 ? U0[4] : U0[0], a0i = b7 ? U0[5] : U0[1];
            const float a1r = b7 ? U0[6] : U0[2], a1i = b7 ? U0[7] : U0[3];
            const float c0r = b6 ? U1[4] : U1[0], c0i = b6 ? U1[5] : U1[1];
            const float c1r = b6 ? U1[6] : U1[2], c1i = b6 ? U1[7] : U1[3];
            // A
            float t0r = a0r*oAr[0] - a0i*oAi[0] + a1r*oAr[2] - a1i*oAi[2];
            float t0i = a0r*oAi[0] + a0i*oAr[0] + a1r*oAi[2] + a1i*oAr[2];
            float t1r = a0r*oAr[1] - a0i*oAi[1] + a1r*oAr[3] - a1i*oAi[3];
            float t1i = a0r*oAi[1] + a0i*oAr[1] + a1r*oAi[3] + a1i*oAr[3];
            arA = c0r*t0r - c0i*t0i + c1r*t1r - c1i*t1i;
            aiA = c0r*t0i + c0i*t0r + c1r*t1i + c1i*t1r;
            // B
            t0r = a0r*oBr[0] - a0i*oBi[0] + a1r*oBr[2] - a1i*oBi[2];
            t0i = a0r*oBi[0] + a0i*oBr[0] + a1r*oBi[2] + a1i*oBr[2];
            t1r = a0r*oBr[1] - a0i*oBi[1] + a1r*oBr[3] - a1i*oBi[3];
            t1i = a0r*oBi[1] + a0i*oBr[1] + a1r*oBi[3] + a1i*oBr[3];
            arB = c0r*t0r - c0i*t0i + c1r*t1r - c1i*t1i;
            aiB = c0r*t0i + c0i*t0r + c1r*t1i + c1i*t1r;
            // C
            t0r = a0r*oCr[0] - a0i*oCi[0] + a1r*oCr[2] - a1i*oCi[2];
            t0i = a0r*oCi[0] + a0i*oCr[0] + a1r*oCi[2] + a1i*oCr[2];
            t1r = a0r*oCr[1] - a0i*oCi[1] + a1r*oCr[3] - a1i*oCi[3];
            t1i = a0r*oCi[1] + a0i*oCr[1] + a1r*oCi[3] + a1i*oCr[3];
            arC = c0r*t0r - c0i*t0i + c1r*t1r - c1i*t1i;
            aiC = c0r*t0i + c0i*t0r + c1r*t1i + c1i*t1r;
        }
        // --- q=2..7: lane-bit gates via shuffles, three chains interleaved ---
        #pragma unroll
        for (int q = 2; q < NQ; ++q) {
            const float* U = &s_U[(l * NQ + q) * 8];
            const int bp  = 7 - q;
            const int bit = (lane >> bp) & 1;
            const float csr = bit ? U[6] : U[0];
            const float csi = bit ? U[7] : U[1];
            const float cpr = bit ? U[4] : U[2];
            const float cpi = bit ? U[5] : U[3];
            const float pAr = __shfl_xor(arA, 1 << bp, 64);
            const float pAi = __shfl_xor(aiA, 1 << bp, 64);
            const float pBr = __shfl_xor(arB, 1 << bp, 64);
            const float pBi = __shfl_xor(aiB, 1 << bp, 64);
            const float pCr = __shfl_xor(arC, 1 << bp, 64);
            const float pCi = __shfl_xor(aiC, 1 << bp, 64);
            const float nAr = csr * arA - csi * aiA + cpr * pAr - cpi * pAi;
            const float nAi = csr * aiA + csi * arA + cpr * pAi + cpi * pAr;
            const float nBr = csr * arB - csi * aiB + cpr * pBr - cpi * pBi;
            const float nBi = csr * aiB + csi * arB + cpr * pBi + cpi * pBr;
            const float nCr = csr * arC - csi * aiC + cpr * pCr - cpi * pCi;
            const float nCi = csr * aiC + csi * arC + cpr * pCi + cpi * pCr;
            arA = nAr; aiA = nAi; arB = nBr; aiB = nBi; arC = nCr; aiC = nCi;
        }
        __syncthreads();                 // all reads of ampc done before overwrite
        ampcA[tid] = make_float2(arA, aiA);
        ampcB[tid] = make_float2(arB, aiB);
        ampcC[tid] = make_float2(arC, aiC);
        __syncthreads();                 // writes visible for next read
    }

    // final CNOT-ring of layer 3: read own permuted amp
    {
        const float2 vA = ampcA[sl ^ pw];
        const float2 vB = ampcB[sl ^ pw];
        const float2 vC = ampcC[sl ^ pw];
        arA = vA.x; aiA = vA.y; arB = vB.x; aiB = vB.y; arC = vC.x; aiC = vC.y;
    }

    // Walsh-Hadamard: per-wave signed butterfly (R10-verified), 3 chains
    {
        const float pA = arA * arA + aiA * aiA;
        const float pB = arB * arB + aiB * aiB;
        const float pC = arC * arC + aiC * aiC;
        float tA = pA, tB = pB, tC = pC;
        #pragma unroll
        for (int d = 0; d < 6; ++d) {
            const float sAs = __shfl_xor(tA, 1 << d, 64);
            const float sBs = __shfl_xor(tB, 1 << d, 64);
            const float sCs = __shfl_xor(tC, 1 << d, 64);
            tA = ((lane >> d) & 1) ? (sAs - tA) : (tA + sAs);
            tB = ((lane >> d) & 1) ? (sBs - tB) : (tB + sBs);
            tC = ((lane >> d) & 1) ? (sCs - tC) : (tC + sCs);
        }
        if (lane == 0) { wpA[w * 7] = tA; wpB[w * 7] = tB; wpC[w * 7] = tC; }
        else if ((lane & (lane - 1)) == 0) {
            const int d = 31 - __clz(lane);                 // lane = 1<<d, d 0..5
            wpA[w * 7 + 1 + d] = tA;                        // qubit 7-d partial
            wpB[w * 7 + 1 + d] = tB;
            wpC[w * 7 + 1 + d] = tC;
        }
    }
    __syncthreads();           // wp visible; wave 3 exits after this

    // waves 0/1/2 -> samples A/B/C (independent heads in parallel)
    if (tid < 192) {
        const int sm = tid >> 6;
        const float* wpp = (sm == 0) ? wpA : (sm == 1) ? wpB : wpC;
        float* sq        = (sm == 0) ? s_qA : (sm == 1) ? s_qB : s_qC;
        const int bb     = (sm == 0) ? iA : (sm == 1) ? iBc : iCc;
        const bool wr    = (sm == 0) || ((sm == 1) ? (iB < Btot) : (iC < Btot));
        // combine Walsh parts -> s_q (same-wave LDS, program-ordered)
        if (lane < 8) {
            float v;
            if (lane == 0)      v = wpp[0] + wpp[7] - wpp[14] - wpp[21];   // bit7
            else if (lane == 1) v = wpp[0] - wpp[7] + wpp[14] - wpp[21];   // bit6
            else {
                const int d = 7 - lane;                                     // q=2..7
                v = wpp[1 + d] + wpp[8 + d] + wpp[15 + d] + wpp[22 + d];
            }
            sq[lane] = v;
        }
        // head layer 1 (lanes 0..31; sq read-after-write, same wave)
        float h = 0.0f;
        if (lane < 32) {
            float acc = head_b1[lane];
            #pragma unroll
            for (int k = 0; k < 8; ++k) acc += head_w1[lane * 14 + k] * sq[k];
            #pragma unroll
            for (int k = 0; k < 6; ++k) acc += head_w1[lane * 14 + 8 + k] * scalars[bb * 6 + k];
            h = fmaxf(acc * (head_bn_g[lane] * BN_RSQ) + head_bn_b[lane], 0.0f);
        }
        // head layer 2: 3 dot-products over 32 h values via butterfly reduce
        float p0 = (lane < 32) ? h * head_w2[lane]      : 0.0f;
        float p1 = (lane < 32) ? h * head_w2[32 + lane] : 0.0f;
        float p2 = (lane < 32) ? h * head_w2[64 + lane] : 0.0f;
        #pragma unroll
        for (int d = 0; d < 6; ++d) {
            p0 += __shfl_xor(p0, 1 << d, 64);
            p1 += __shfl_xor(p1, 1 << d, 64);
            p2 += __shfl_xor(p2, 1 << d, 64);
        }
        if (lane < 3 && wr) {
            const float v = (lane == 0) ? p0 : ((lane == 1) ? p1 : p2);
            out[bb * 3 + lane] = v + head_b2[lane];
        }
    }
}

extern "C" void kernel_launch(void* const* d_in, const int* in_sizes, int n_in,
                              void* d_out, int out_size, void* d_ws, size_t ws_size,
                              hipStream_t stream) {
    const float* flux      = (const float*)d_in[0];
    const float* scalars   = (const float*)d_in[1];
    const float* conv1_w   = (const float*)d_in[2];
    const float* bn1_g     = (const float*)d_in[3];
    const float* bn1_b     = (const float*)d_in[4];
    const float* conv2_w   = (const float*)d_in[5];
    const float* bn2_g     = (const float*)d_in[6];
    const float* bn2_b     = (const float*)d_in[7];
    const float* proj_w1   = (const float*)d_in[8];
    const float* proj_b1   = (const float*)d_in[9];
    const float* proj_w2   = (const float*)d_in[10];
    const float* proj_b2   = (const float*)d_in[11];
    const float* q_weights = (const float*)d_in[12];
    const float* head_w1   = (const float*)d_in[13];
    const float* head_b1   = (const float*)d_in[14];
    const float* head_bn_g = (const float*)d_in[15];
    const float* head_bn_b = (const float*)d_in[16];
    const float* head_w2   = (const float*)d_in[17];
    const float* head_b2   = (const float*)d_in[18];

    const int B  = in_sizes[0] / L0;   // 4096
    const int nB = (B + 2) / 3;        // 1366

    aec_fused_kernel<<<dim3(nB), dim3(256), SHBYTES, stream>>>(
        flux, scalars, conv1_w, bn1_g, bn1_b, conv2_w, bn2_g, bn2_b,
        proj_w1, proj_b1, proj_w2, proj_b2, q_weights,
        head_w1, head_b1, head_bn_g, head_bn_b, head_w2, head_b2,
        (float*)d_out, B);
}